// Round 8
// baseline (58.861 us; speedup 1.0000x reference)
//
#include <hip/hip_runtime.h>
#include <hip/hip_bf16.h>

#define TWO_N 8192
#define NHALF 4096
#define D 256
#define NTILE 64            // 8192 / 128 tiles per dimension
#define BLK_ELEMS 32768     // 32 kchunks * 128 rows * 8 elems per 128-row block
static constexpr float INV_T = 2.0f; // 1 / 0.5

typedef __attribute__((ext_vector_type(8))) short short8;
typedef __attribute__((ext_vector_type(4))) float f32x4;

__device__ __forceinline__ ushort f2bfu(float f) {
    __hip_bfloat16 b = __float2bfloat16(f);
    return *reinterpret_cast<ushort*>(&b);
}

// ------ kernel 1: fused normalize + positive-pair sim, blocked-K-major out --
// znb layout: [rowblock(64)][kchunk(32)][row-in-block(128)][elem(8)]
//   flat = ((row>>7)*32 + (col>>3))*1024 + (row&127)*8 + (col&7)
// Each MFMA fragment read (16 lanes x 16B, same kchunk, consecutive rows) is
// 256B contiguous in global memory -> fully coalesced direct-to-VGPR loads.
__global__ __launch_bounds__(256) void norm_pos_kernel(
        const float* __restrict__ z_i, const float* __restrict__ z_j,
        ushort* __restrict__ znb, float* __restrict__ sim_pos,
        float* __restrict__ denom) {
    const int wid = threadIdx.x >> 6, lane = threadIdx.x & 63;
    const int i = blockIdx.x * 4 + wid;  // 0..4095
    const float4 vi = *reinterpret_cast<const float4*>(z_i + (size_t)i * D + lane * 4);
    const float4 vj = *reinterpret_cast<const float4*>(z_j + (size_t)i * D + lane * 4);
    float ssi = vi.x * vi.x + vi.y * vi.y + vi.z * vi.z + vi.w * vi.w;
    float ssj = vj.x * vj.x + vj.y * vj.y + vj.z * vj.z + vj.w * vj.w;
    float dt  = vi.x * vj.x + vi.y * vj.y + vi.z * vj.z + vi.w * vj.w;
    #pragma unroll
    for (int off = 32; off; off >>= 1) {
        ssi += __shfl_xor(ssi, off);
        ssj += __shfl_xor(ssj, off);
        dt  += __shfl_xor(dt,  off);
    }
    const float ri = rsqrtf(ssi), rj = rsqrtf(ssj);
    ushort4 oi, oj;
    oi.x = f2bfu(vi.x * ri); oi.y = f2bfu(vi.y * ri);
    oi.z = f2bfu(vi.z * ri); oi.w = f2bfu(vi.w * ri);
    oj.x = f2bfu(vj.x * rj); oj.y = f2bfu(vj.y * rj);
    oj.z = f2bfu(vj.z * rj); oj.w = f2bfu(vj.w * rj);
    // cols lane*4..lane*4+3: kchunk = lane>>1, e = (lane&1)*4
    const int c = lane >> 1, e = (lane & 1) * 4;
    const int i2 = i + NHALF;
    const size_t bi = ((size_t)(i  >> 7) * 32 + c) * 1024 + (i  & 127) * 8 + e;
    const size_t bj = ((size_t)(i2 >> 7) * 32 + c) * 1024 + (i2 & 127) * 8 + e;
    *reinterpret_cast<ushort4*>(znb + bi) = oi;
    *reinterpret_cast<ushort4*>(znb + bj) = oj;
    if (lane == 0) {
        const float sp = dt * ri * rj * INV_T;
        sim_pos[i] = sp;
        sim_pos[i + NHALF] = sp;   // symmetric
        denom[i] = 0.0f;
        denom[i + NHALF] = 0.0f;
    }
}

// ------ kernel 2: fused symmetric sim-GEMM + exp + row/col sums ------
// BM=BN=128, 4 waves (2x2), per-wave 64x64, mfma_f32_16x16x32_bf16.
// NO LDS, NO barriers: fragments loaded directly global->VGPR from the
// blocked layout (L2-resident 4MB; each fragment load = 256B contiguous per
// 16-lane group). K fully unrolled: 64 independent 16B loads + 128 MFMAs per
// thread; latency hidden by TLP (no LDS/VGPR occupancy bound) + compiler
// pipelining. Fragment math and epilogue identical to R7.
__global__ __launch_bounds__(256) void gemm_denom_kernel(
        const ushort* __restrict__ znb, float* __restrict__ denom) {
    const int tr = blockIdx.x;
    const int tc = blockIdx.y;
    if (tc < tr) return;  // block-uniform exit

    const int tid  = threadIdx.x;
    const int lane = tid & 63;
    const int wid  = tid >> 6;
    const int wr   = wid >> 1;
    const int wc   = wid & 1;
    const int r16  = lane & 15;
    const int kgrp = lane >> 4;
    const int row0 = tr * 128;
    const int col0 = tc * 128;

    // per-lane fragment base: kchunk = ks*4 + kgrp, row_in_block = .. + r16
    // elem offset = kchunk*1024 + row_in_block*8
    const ushort* pA = znb + (size_t)tr * BLK_ELEMS + kgrp * 1024 + (wr * 64 + r16) * 8;
    const ushort* pB = znb + (size_t)tc * BLK_ELEMS + kgrp * 1024 + (wc * 64 + r16) * 8;

    f32x4 acc[4][4];
    #pragma unroll
    for (int m = 0; m < 4; ++m)
        #pragma unroll
        for (int n = 0; n < 4; ++n) {
            f32x4 z = {0.f, 0.f, 0.f, 0.f};
            acc[m][n] = z;
        }

    #pragma unroll
    for (int ks = 0; ks < 8; ++ks) {
        short8 a[4], b[4];
        #pragma unroll
        for (int m = 0; m < 4; ++m)
            a[m] = *reinterpret_cast<const short8*>(pA + ks * 4096 + m * 128);
        #pragma unroll
        for (int n = 0; n < 4; ++n)
            b[n] = *reinterpret_cast<const short8*>(pB + ks * 4096 + n * 128);
        #pragma unroll
        for (int m = 0; m < 4; ++m)
            #pragma unroll
            for (int n = 0; n < 4; ++n)
                acc[m][n] = __builtin_amdgcn_mfma_f32_16x16x32_bf16(
                    a[m], b[n], acc[m][n], 0, 0, 0);
    }

    // ---- epilogue: exp, diag zero, row sums (+ col sums if off-diagonal) ----
    const bool offdiag = (tr != tc);
    float cs[4] = {0.f, 0.f, 0.f, 0.f};
    #pragma unroll
    for (int m = 0; m < 4; ++m) {
        #pragma unroll
        for (int reg = 0; reg < 4; ++reg) {
            const int rg = row0 + wr * 64 + m * 16 + kgrp * 4 + reg;
            float rs = 0.f;
            #pragma unroll
            for (int n = 0; n < 4; ++n) {
                const int cg = col0 + wc * 64 + n * 16 + r16;
                float e = __expf(acc[m][n][reg] * INV_T);
                if (rg == cg) e = 0.f;   // only possible when tr==tc
                rs += e;
                cs[n] += e;
            }
            rs += __shfl_xor(rs, 1);
            rs += __shfl_xor(rs, 2);
            rs += __shfl_xor(rs, 4);
            rs += __shfl_xor(rs, 8);
            if (r16 == 0) atomicAdd(&denom[rg], rs);
        }
    }
    if (offdiag) {
        #pragma unroll
        for (int n = 0; n < 4; ++n) {
            cs[n] += __shfl_xor(cs[n], 16);
            cs[n] += __shfl_xor(cs[n], 32);
        }
        if (kgrp == 0) {
            #pragma unroll
            for (int n = 0; n < 4; ++n)
                atomicAdd(&denom[col0 + wc * 64 + n * 16 + r16], cs[n]);
        }
    }
}

// ---------------- kernel 3: final loss reduction ----------------
__global__ __launch_bounds__(1024) void final_kernel(
        const float* __restrict__ sim_pos, const float* __restrict__ denom,
        float* __restrict__ out) {
    const int tid = threadIdx.x;
    float s = 0.f;
    for (int i = tid; i < TWO_N; i += 1024)
        s += sim_pos[i] - logf(denom[i]);
    #pragma unroll
    for (int off = 32; off; off >>= 1) s += __shfl_down(s, off);
    __shared__ float red[16];
    const int wid = tid >> 6, lane = tid & 63;
    if (lane == 0) red[wid] = s;
    __syncthreads();
    if (tid == 0) {
        float t = 0.f;
        #pragma unroll
        for (int w = 0; w < 16; ++w) t += red[w];
        out[0] = -t / (float)TWO_N;
    }
}

extern "C" void kernel_launch(void* const* d_in, const int* in_sizes, int n_in,
                              void* d_out, int out_size, void* d_ws, size_t ws_size,
                              hipStream_t stream) {
    const float* z_i = (const float*)d_in[0];
    const float* z_j = (const float*)d_in[1];
    float* out = (float*)d_out;

    ushort* znb     = (ushort*)d_ws;                                  // 4 MB
    float*  sim_pos = (float*)((char*)d_ws + (size_t)TWO_N * D * 2);  // 32 KB
    float*  denom   = sim_pos + TWO_N;                                // 32 KB

    norm_pos_kernel<<<NHALF / 4, 256, 0, stream>>>(z_i, z_j, znb, sim_pos, denom);
    dim3 grid(NTILE, NTILE);
    gemm_denom_kernel<<<grid, 256, 0, stream>>>(znb, denom);
    final_kernel<<<1, 1024, 0, stream>>>(sim_pos, denom, out);
}

// Round 9
// 57.920 us; speedup vs baseline: 1.0163x; 1.0163x over previous
//
#include <hip/hip_runtime.h>
#include <hip/hip_bf16.h>

#define TWO_N 8192
#define NHALF 4096
#define D 256
#define NTILE 64            // 8192 / 128 tiles per dimension
#define NTRI  2080          // NTILE*(NTILE+1)/2 live (upper-triangle) tiles
#define NBLK  1040          // persistent blocks; each handles 2 adjacent tiles
#define BLK_ELEMS 32768     // 32 kchunks * 128 rows * 8 elems per 128-row block
static constexpr float INV_T = 2.0f; // 1 / 0.5

typedef __attribute__((ext_vector_type(8))) short short8;
typedef __attribute__((ext_vector_type(4))) float f32x4;

__device__ __forceinline__ ushort f2bfu(float f) {
    __hip_bfloat16 b = __float2bfloat16(f);
    return *reinterpret_cast<ushort*>(&b);
}

// ------ kernel 1: fused normalize + positive-pair sim, blocked-K-major out --
// znb layout: [rowblock(64)][kchunk(32)][row-in-block(128)][elem(8)]
//   flat = ((row>>7)*32 + (col>>3))*1024 + (row&127)*8 + (col&7)
__global__ __launch_bounds__(256) void norm_pos_kernel(
        const float* __restrict__ z_i, const float* __restrict__ z_j,
        ushort* __restrict__ znb, float* __restrict__ sim_pos,
        float* __restrict__ denom) {
    const int wid = threadIdx.x >> 6, lane = threadIdx.x & 63;
    const int i = blockIdx.x * 4 + wid;  // 0..4095
    const float4 vi = *reinterpret_cast<const float4*>(z_i + (size_t)i * D + lane * 4);
    const float4 vj = *reinterpret_cast<const float4*>(z_j + (size_t)i * D + lane * 4);
    float ssi = vi.x * vi.x + vi.y * vi.y + vi.z * vi.z + vi.w * vi.w;
    float ssj = vj.x * vj.x + vj.y * vj.y + vj.z * vj.z + vj.w * vj.w;
    float dt  = vi.x * vj.x + vi.y * vj.y + vi.z * vj.z + vi.w * vj.w;
    #pragma unroll
    for (int off = 32; off; off >>= 1) {
        ssi += __shfl_xor(ssi, off);
        ssj += __shfl_xor(ssj, off);
        dt  += __shfl_xor(dt,  off);
    }
    const float ri = rsqrtf(ssi), rj = rsqrtf(ssj);
    ushort4 oi, oj;
    oi.x = f2bfu(vi.x * ri); oi.y = f2bfu(vi.y * ri);
    oi.z = f2bfu(vi.z * ri); oi.w = f2bfu(vi.w * ri);
    oj.x = f2bfu(vj.x * rj); oj.y = f2bfu(vj.y * rj);
    oj.z = f2bfu(vj.z * rj); oj.w = f2bfu(vj.w * rj);
    const int c = lane >> 1, e = (lane & 1) * 4;
    const int i2 = i + NHALF;
    const size_t bi = ((size_t)(i  >> 7) * 32 + c) * 1024 + (i  & 127) * 8 + e;
    const size_t bj = ((size_t)(i2 >> 7) * 32 + c) * 1024 + (i2 & 127) * 8 + e;
    *reinterpret_cast<ushort4*>(znb + bi) = oi;
    *reinterpret_cast<ushort4*>(znb + bj) = oj;
    if (lane == 0) {
        const float sp = dt * ri * rj * INV_T;
        sim_pos[i] = sp;
        sim_pos[i + NHALF] = sp;   // symmetric
        denom[i] = 0.0f;
        denom[i + NHALF] = 0.0f;
    }
}

// ------ kernel 2: persistent fused symmetric sim-GEMM + exp + row/col sums --
// 1040 persistent blocks (~4/CU, all live, equal work) x 2 adjacent triangle
// tiles each -> guaranteed ~16 resident waves/CU for latency hiding; adjacent
// tiles share the A panel (warm L1/L2 on the 2nd tile).
// Per tile: BM=BN=128, 4 waves (2x2), per-wave 64x64, direct global->VGPR
// fragment loads from the blocked layout (no LDS, no barriers). Body/epilogue
// identical to R8; residency is the only variable vs R8.
__global__ __launch_bounds__(256, 4) void gemm_denom_kernel(
        const ushort* __restrict__ znb, float* __restrict__ denom) {
    const int tid  = threadIdx.x;
    const int lane = tid & 63;
    const int wid  = tid >> 6;
    const int wr   = wid >> 1;
    const int wc   = wid & 1;
    const int r16  = lane & 15;
    const int kgrp = lane >> 4;

    // decode first tile index (triangle row-major): idx0 = 2*blockIdx.x
    int rem = blockIdx.x * 2;
    int tr = 0;
    while (rem >= NTILE - tr) { rem -= NTILE - tr; ++tr; }

    #pragma unroll
    for (int t = 0; t < 2; ++t) {
        const int tc = tr + rem;
        const int row0 = tr * 128;
        const int col0 = tc * 128;

        const ushort* pA = znb + (size_t)tr * BLK_ELEMS + kgrp * 1024 + (wr * 64 + r16) * 8;
        const ushort* pB = znb + (size_t)tc * BLK_ELEMS + kgrp * 1024 + (wc * 64 + r16) * 8;

        f32x4 acc[4][4];
        #pragma unroll
        for (int m = 0; m < 4; ++m)
            #pragma unroll
            for (int n = 0; n < 4; ++n) {
                f32x4 z = {0.f, 0.f, 0.f, 0.f};
                acc[m][n] = z;
            }

        #pragma unroll
        for (int ks = 0; ks < 8; ++ks) {
            short8 a[4], b[4];
            #pragma unroll
            for (int m = 0; m < 4; ++m)
                a[m] = *reinterpret_cast<const short8*>(pA + ks * 4096 + m * 128);
            #pragma unroll
            for (int n = 0; n < 4; ++n)
                b[n] = *reinterpret_cast<const short8*>(pB + ks * 4096 + n * 128);
            #pragma unroll
            for (int m = 0; m < 4; ++m)
                #pragma unroll
                for (int n = 0; n < 4; ++n)
                    acc[m][n] = __builtin_amdgcn_mfma_f32_16x16x32_bf16(
                        a[m], b[n], acc[m][n], 0, 0, 0);
        }

        // epilogue: exp, diag zero, row sums (+ col sums if off-diagonal)
        const bool offdiag = (tr != tc);
        float cs[4] = {0.f, 0.f, 0.f, 0.f};
        #pragma unroll
        for (int m = 0; m < 4; ++m) {
            #pragma unroll
            for (int reg = 0; reg < 4; ++reg) {
                const int rg = row0 + wr * 64 + m * 16 + kgrp * 4 + reg;
                float rs = 0.f;
                #pragma unroll
                for (int n = 0; n < 4; ++n) {
                    const int cg = col0 + wc * 64 + n * 16 + r16;
                    float e = __expf(acc[m][n][reg] * INV_T);
                    if (rg == cg) e = 0.f;   // only possible when tr==tc
                    rs += e;
                    cs[n] += e;
                }
                rs += __shfl_xor(rs, 1);
                rs += __shfl_xor(rs, 2);
                rs += __shfl_xor(rs, 4);
                rs += __shfl_xor(rs, 8);
                if (r16 == 0) atomicAdd(&denom[rg], rs);
            }
        }
        if (offdiag) {
            #pragma unroll
            for (int n = 0; n < 4; ++n) {
                cs[n] += __shfl_xor(cs[n], 16);
                cs[n] += __shfl_xor(cs[n], 32);
            }
            if (kgrp == 0) {
                #pragma unroll
                for (int n = 0; n < 4; ++n)
                    atomicAdd(&denom[col0 + wc * 64 + n * 16 + r16], cs[n]);
            }
        }

        // advance to next triangle tile (idx0 + 1)
        if (++rem >= NTILE - tr) { rem = 0; ++tr; }
    }
}

// ---------------- kernel 3: final loss reduction ----------------
__global__ __launch_bounds__(1024) void final_kernel(
        const float* __restrict__ sim_pos, const float* __restrict__ denom,
        float* __restrict__ out) {
    const int tid = threadIdx.x;
    float s = 0.f;
    for (int i = tid; i < TWO_N; i += 1024)
        s += sim_pos[i] - logf(denom[i]);
    #pragma unroll
    for (int off = 32; off; off >>= 1) s += __shfl_down(s, off);
    __shared__ float red[16];
    const int wid = tid >> 6, lane = tid & 63;
    if (lane == 0) red[wid] = s;
    __syncthreads();
    if (tid == 0) {
        float t = 0.f;
        #pragma unroll
        for (int w = 0; w < 16; ++w) t += red[w];
        out[0] = -t / (float)TWO_N;
    }
}

extern "C" void kernel_launch(void* const* d_in, const int* in_sizes, int n_in,
                              void* d_out, int out_size, void* d_ws, size_t ws_size,
                              hipStream_t stream) {
    const float* z_i = (const float*)d_in[0];
    const float* z_j = (const float*)d_in[1];
    float* out = (float*)d_out;

    ushort* znb     = (ushort*)d_ws;                                  // 4 MB
    float*  sim_pos = (float*)((char*)d_ws + (size_t)TWO_N * D * 2);  // 32 KB
    float*  denom   = sim_pos + TWO_N;                                // 32 KB

    norm_pos_kernel<<<NHALF / 4, 256, 0, stream>>>(z_i, z_j, znb, sim_pos, denom);
    gemm_denom_kernel<<<NBLK, 256, 0, stream>>>(znb, denom);
    final_kernel<<<1, 1024, 0, stream>>>(sim_pos, denom, out);
}